// Round 1
// baseline (232.871 us; speedup 1.0000x reference)
//
#include <hip/hip_runtime.h>
#include <stdint.h>

// TopkActivation: per-row top-k (k=64) over H=32768 fp32, scatter back into zeros.
// One block per row; whole row staged in registers (32 uints/thread) so the
// input is read from HBM exactly once. Radix-select via 4096-bin histogram of
// the top 12 monotonic-key bits; tie-exact candidate ranking matches
// jax.lax.top_k semantics (equal values -> lower index first).

#define H_DIM    32768
#define NTHREADS 1024
#define VPT      (H_DIM / NTHREADS / 4)   // 8 float4 per thread
#define CAP      2048
#define NBINS    4096

__device__ __forceinline__ uint32_t f2mono(float f) {
    uint32_t u = __float_as_uint(f);
    // order-preserving map: descending float order == descending uint order
    return (u & 0x80000000u) ? ~u : (u | 0x80000000u);
}
__device__ __forceinline__ float mono2f(uint32_t m) {
    uint32_t u = (m & 0x80000000u) ? (m & 0x7fffffffu) : ~m;
    return __uint_as_float(u);
}

__global__ __launch_bounds__(NTHREADS)
void topk_kernel(const float* __restrict__ in, const int* __restrict__ kp,
                 float* __restrict__ out)
{
    __shared__ uint32_t hist[NBINS];
    __shared__ uint32_t wave_exc[16];
    __shared__ uint32_t s_b, s_g, s_cnt;
    __shared__ uint32_t s_ncand;
    __shared__ uint32_t cand_u[CAP];
    __shared__ uint32_t cand_i[CAP];

    const uint32_t t   = threadIdx.x;
    const uint32_t row = blockIdx.x;
    const uint32_t k   = (uint32_t)kp[0];

    const float4* __restrict__ rin  = (const float4*)(in  + (size_t)row * H_DIM);
    float4*       __restrict__ rout = (float4*)(out + (size_t)row * H_DIM);

    #pragma unroll
    for (int i = 0; i < NBINS / NTHREADS; ++i) hist[t + i * NTHREADS] = 0;
    if (t == 0) s_ncand = 0;
    __syncthreads();

    // ---- pass A: load row -> registers (monotonic keys) + 12-bit histogram
    uint32_t um[VPT][4];
    #pragma unroll
    for (int it = 0; it < VPT; ++it) {
        float4 v = rin[t + it * NTHREADS];
        um[it][0] = f2mono(v.x);
        um[it][1] = f2mono(v.y);
        um[it][2] = f2mono(v.z);
        um[it][3] = f2mono(v.w);
        atomicAdd(&hist[um[it][0] >> 20], 1u);
        atomicAdd(&hist[um[it][1] >> 20], 1u);
        atomicAdd(&hist[um[it][2] >> 20], 1u);
        atomicAdd(&hist[um[it][3] >> 20], 1u);
    }
    __syncthreads();

    // ---- find boundary bin b: cumAbove(b) < k <= cumAbove(b) + hist[b]
    {
        uint32_t h0 = hist[4*t], h1 = hist[4*t+1], h2 = hist[4*t+2], h3 = hist[4*t+3];
        uint32_t s = h0 + h1 + h2 + h3;
        uint32_t lane = t & 63, wid = t >> 6;
        uint32_t v = s;
        // inclusive suffix-scan within wave (sum over lanes >= lane)
        #pragma unroll
        for (int off = 1; off < 64; off <<= 1) {
            uint32_t o = __shfl_down(v, off);
            if (lane + off < 64) v += o;
        }
        if (lane == 0) wave_exc[wid] = v;   // wave total
        __syncthreads();
        if (t == 0) {                        // exclusive suffix over the 16 waves
            uint32_t acc = 0;
            for (int w = 15; w >= 0; --w) { uint32_t tw = wave_exc[w]; wave_exc[w] = acc; acc += tw; }
        }
        __syncthreads();
        uint32_t cumIncl = v + wave_exc[wid];   // sum over 4-bin chunks >= t
        uint32_t Ech = cumIncl - s;             // sum over chunks strictly above t
        if (Ech < k && k <= Ech + s) {          // exactly one thread matches
            uint32_t gl = Ech;
            #pragma unroll
            for (int bb = 3; bb >= 0; --bb) {
                uint32_t h = hist[4*t + bb];
                if (gl + h >= k) { s_b = 4*t + (uint32_t)bb; s_g = gl; s_cnt = h; break; }
                gl += h;
            }
        }
    }
    __syncthreads();

    uint32_t prefix = s_b;
    uint32_t g      = s_g;     // count strictly above the boundary range
    uint32_t cnt    = s_cnt;   // count inside the boundary range
    uint32_t shift  = 20;

    // ---- rare fallback: refine prefix until candidates fit in CAP
    while (cnt > CAP && shift > 0) {
        uint32_t nshift = (shift >= 12) ? (shift - 12) : 0;
        uint32_t nbits  = shift - nshift;
        uint32_t nbins  = 1u << nbits;
        __syncthreads();
        for (uint32_t i = t; i < nbins; i += NTHREADS) hist[i] = 0;
        __syncthreads();
        #pragma unroll
        for (int it = 0; it < VPT; ++it) {
            #pragma unroll
            for (int c = 0; c < 4; ++c) {
                uint32_t u = um[it][c];
                if ((u >> shift) == prefix)
                    atomicAdd(&hist[(u >> nshift) & (nbins - 1)], 1u);
            }
        }
        __syncthreads();
        if (t == 0) {
            uint32_t gl = g;
            for (int bb = (int)nbins - 1; bb >= 0; --bb) {
                uint32_t h = hist[bb];
                if (gl + h >= k) { s_b = (uint32_t)bb; s_g = gl; s_cnt = h; break; }
                gl += h;
            }
        }
        __syncthreads();
        prefix = (prefix << nbits) | s_b;
        g = s_g; cnt = s_cnt; shift = nshift;
    }

    // ---- pass B: write output from registers; collect boundary candidates
    const uint32_t need = k - g;
    #pragma unroll
    for (int it = 0; it < VPT; ++it) {
        float4 o;
        float* oc = (float*)&o;
        #pragma unroll
        for (int c = 0; c < 4; ++c) {
            uint32_t u  = um[it][c];
            uint32_t hi = u >> shift;
            float val = 0.0f;
            if (hi > prefix) {
                val = mono2f(u);
            } else if (hi == prefix) {
                uint32_t p = atomicAdd(&s_ncand, 1u);
                if (p < CAP) { cand_u[p] = u; cand_i[p] = (t + (uint32_t)it * NTHREADS) * 4u + (uint32_t)c; }
            }
            oc[c] = val;
        }
        rout[t + it * NTHREADS] = o;
    }
    __syncthreads();

    // ---- rank candidates: (value desc, index asc); first `need` win
    uint32_t nc = s_ncand; if (nc > CAP) nc = CAP;
    for (uint32_t i = t; i < nc; i += NTHREADS) {
        uint32_t ui = cand_u[i], ii = cand_i[i];
        uint32_t rank = 0;
        for (uint32_t j = 0; j < nc; ++j) {
            uint32_t uj = cand_u[j];
            rank += (uj > ui || (uj == ui && cand_i[j] < ii)) ? 1u : 0u;
        }
        if (rank < need) out[(size_t)row * H_DIM + ii] = mono2f(ui);
    }
}

extern "C" void kernel_launch(void* const* d_in, const int* in_sizes, int n_in,
                              void* d_out, int out_size, void* d_ws, size_t ws_size,
                              hipStream_t stream)
{
    const float* x  = (const float*)d_in[0];
    const int*   kp = (const int*)d_in[1];
    float* out = (float*)d_out;
    const int B = in_sizes[0] / H_DIM;
    hipLaunchKernelGGL(topk_kernel, dim3(B), dim3(NTHREADS), 0, stream, x, kp, out);
}